// Round 3
// baseline (357.277 us; speedup 1.0000x reference)
//
#include <hip/hip_runtime.h>

// Problem constants: B=2, C=64, H=W=256, KS=3, PAD=1, N=9, O=64
// Inputs NCHW fp32; activations internally NHWC bf16: addr = (h*256+w)*64 + c.
// Contraction index k = n*64 + c (n = 3x3 tap, c = channel).

typedef __attribute__((ext_vector_type(8))) short short8;     // 8 bf16 = 4 VGPRs
typedef __attribute__((ext_vector_type(4))) float float4a;    // MFMA accumulator

// packed fp32x2 -> bf16x2 via HW cvt (RNE), 1 VALU op (gfx950; no builtin)
static __device__ __forceinline__ unsigned int cvtpk(float lo, float hi) {
    unsigned int r;
    asm("v_cvt_pk_bf16_f32 %0, %1, %2" : "=v"(r) : "v"(lo), "v"(hi));
    return r;
}
// single fp32 -> bf16 bits
static __device__ __forceinline__ unsigned short f2bf(float f) {
    return (unsigned short)(cvtpk(f, f) & 0xffffu);
}
// low/high bf16 of a dword -> fp32 (hi is a single AND)
static __device__ __forceinline__ float bflo(unsigned int u) {
    return __builtin_bit_cast(float, u << 16);
}
static __device__ __forceinline__ float bfhi(unsigned int u) {
    return __builtin_bit_cast(float, u & 0xffff0000u);
}
// bilinear-combine two packed bf16 channels across 4 corners
static __device__ __forceinline__ unsigned int comb2(unsigned int A, unsigned int B,
                                                     unsigned int C, unsigned int D,
                                                     float4 G) {
    const float lo = G.x * bflo(A) + G.y * bflo(B) + G.z * bflo(C) + G.w * bflo(D);
    const float hi = G.x * bfhi(A) + G.y * bfhi(B) + G.z * bfhi(C) + G.w * bfhi(D);
    return cvtpk(lo, hi);
}

// ---------------------------------------------------------------------------
// One kernel packs all four weight tensors (saves 3 launches).
// w_conv [o][c][n] -> bf16 [o][k=n*64+c]; w_off [oc][c][n] -> bf16 [32][k], pad 0.
__global__ __launch_bounds__(256) void k_pack_all(const float* __restrict__ w1,
                                                  const float* __restrict__ w2,
                                                  const float* __restrict__ wo1,
                                                  const float* __restrict__ wo2,
                                                  unsigned short* __restrict__ w1b,
                                                  unsigned short* __restrict__ w2b,
                                                  unsigned short* __restrict__ wob1,
                                                  unsigned short* __restrict__ wob2) {
    int i = blockIdx.x * 256 + threadIdx.x;
    if (i < 36864) {
        int o = i / 576, r = i - o * 576, n = r >> 6, c = r & 63;
        w1b[i] = f2bf(w1[o * 576 + c * 9 + n]);
    } else if (i < 73728) {
        int j = i - 36864;
        int o = j / 576, r = j - o * 576, n = r >> 6, c = r & 63;
        w2b[j] = f2bf(w2[o * 576 + c * 9 + n]);
    } else if (i < 92160) {
        int j = i - 73728;
        int oc = j / 576, r = j - oc * 576, n = r >> 6, c = r & 63;
        wob1[j] = (oc < 18) ? f2bf(wo1[oc * 576 + c * 9 + n]) : (unsigned short)0;
    } else if (i < 110592) {
        int j = i - 92160;
        int oc = j / 576, r = j - oc * 576, n = r >> 6, c = r & 63;
        wob2[j] = (oc < 18) ? f2bf(wo2[oc * 576 + c * 9 + n]) : (unsigned short)0;
    }
}

// ---------------------------------------------------------------------------
// NCHW fp32 [64][65536] -> NHWC bf16 [65536][64]; grid (1024, B).
__global__ __launch_bounds__(256) void k_transpose_bf(const float* __restrict__ x,
                                                      unsigned short* __restrict__ xt) {
    __shared__ float tile[64][65];
    const float* xb = x + (size_t)blockIdx.y * 4194304;
    unsigned short* xtb = xt + (size_t)blockIdx.y * 4194304;
    const int p0 = blockIdx.x << 6;
    const int p = threadIdx.x & 63;
    const int c0 = threadIdx.x >> 6;   // 0..3
    #pragma unroll
    for (int i = 0; i < 16; ++i) {
        const int c = (i << 2) + c0;
        tile[p][c] = xb[(c << 16) + p0 + p];
    }
    __syncthreads();
    const int cq = (threadIdx.x & 15) << 2;
    const int pr0 = threadIdx.x >> 4;
    #pragma unroll
    for (int j = 0; j < 4; ++j) {
        const int pr = (j << 4) + pr0;
        uint2 u;
        u.x = cvtpk(tile[pr][cq + 0], tile[pr][cq + 1]);
        u.y = cvtpk(tile[pr][cq + 2], tile[pr][cq + 3]);
        *(uint2*)(xtb + ((p0 + pr) << 6) + cq) = u;
    }
}

// ---------------------------------------------------------------------------
// Fused deformable conv layer, bf16 NHWC src. NEW (r3): LDS-windowed gather.
// Block = 128 thr = 2 waves, 32 px of one row. Stage a 7-row x 40-col x 64-ch
// bf16 window (rows h-3..h+3, cols w0-3..w0+36) to LDS once (coalesced,
// XOR-swizzled 16B slots). Then each wave handles its 16 px end-to-end with
// NO further barriers:
//   - offset conv reads its im2col directly from the window (sliding 3x3),
//   - bilinear corners are ds_read_b128 from the window; results are built
//     in-register directly as conv MFMA A-fragments (lane l = px l&15,
//     oct q=l>>4 for even-ks frag, q+4 for odd-ks frag),
//   - rare out-of-window corners (|offset|>~2) take a global-load fallback.
// L1 line traffic per 16px drops ~3600 -> ~2300; gathers move to the LDS pipe.
#define WROWS 7
#define WCOLS 40

__global__ __launch_bounds__(128, 2) void k_fused(const unsigned short* __restrict__ src,
                                                  const unsigned short* __restrict__ wob,
                                                  const float* __restrict__ b_off,
                                                  const unsigned short* __restrict__ wtb,
                                                  const float* __restrict__ addsrc,
                                                  void* __restrict__ out,
                                                  int relu, int nhwc_out) {
    __shared__ unsigned short s_win[WROWS * WCOLS * 64];   // 35840 B
    __shared__ float          s_soff[2 * 320];             // 2560 B (total 38400)

    const int b = blockIdx.z;
    const int h = blockIdx.y;
    const int w0 = blockIdx.x << 5;          // 32 px per block
    const int tid = threadIdx.x;
    const int lane = tid & 63;
    const int wv = tid >> 6;                 // wave 0/1
    const int l16 = lane & 15;               // px within wave tile (and oc col)
    const int q = lane >> 4;                 // 0..3 (channel-octet low half)
    const int pxb = wv << 4;                 // wave's px base within block
    const unsigned short* srcb = src + ((size_t)b << 22);   // b*65536*64

    // ========== Stage window: rows h-3..h+3, cols w0-3..w0+36, swizzled ======
    // chunk i -> (r = i/320, cl = (i>>3)%40, o = i&7); 16B per chunk.
    // LDS slot: phys_oct = o ^ (cl&7) spreads the 128B-stride columns over banks.
    #pragma unroll
    for (int it = 0; it < 18; ++it) {
        const int i = it * 128 + tid;
        if (i < 2240) {
            const int o = i & 7;
            const int t = i >> 3;
            const int r = t / 40;
            const int cl = t - r * 40;
            const int row = h - 3 + r;
            const int col = w0 - 3 + cl;
            const bool inb = (row >= 0) && (row < 256) && (col >= 0) && (col < 256);
            const int lin = inb ? ((row << 8) + col) : 0;
            uint4 v = *(const uint4*)(srcb + (lin << 6) + (o << 3));
            if (!inb) { v.x = 0u; v.y = 0u; v.z = 0u; v.w = 0u; }
            *(uint4*)(s_win + ((r * WCOLS + cl) << 6) + ((o ^ (cl & 7)) << 3)) = v;
        }
    }
    __syncthreads();   // the ONLY barrier

    // ============ Offset conv: im2col straight from the window ============
    float4a aO0 = {0.f, 0.f, 0.f, 0.f};   // oc 0..15
    float4a aO1 = {0.f, 0.f, 0.f, 0.f};   // oc 16..31 (only 16,17 used)
    {
        const unsigned short* bo0 = wob + l16 * 576 + (q << 3);
        const unsigned short* bo1 = wob + (16 + l16) * 576 + (q << 3);
        #pragma unroll
        for (int n = 0; n < 9; ++n) {
            const int rn = n / 3, cn = n - rn * 3;
            const int cl = pxb + l16 + cn + 2;     // window col of (px, tap n)
            const int sw = cl & 7;
            const unsigned short* cell = s_win + (((rn + 2) * WCOLS + cl) << 6);
            const short8 a0 = *(const short8*)(cell + ((q ^ sw) << 3));
            const short8 a1 = *(const short8*)(cell + (((q + 4) ^ sw) << 3));
            const short8 wf0a = *(const short8*)(bo0 + n * 64);
            const short8 wf0b = *(const short8*)(bo0 + n * 64 + 32);
            const short8 wf1a = *(const short8*)(bo1 + n * 64);
            const short8 wf1b = *(const short8*)(bo1 + n * 64 + 32);
            aO0 = __builtin_amdgcn_mfma_f32_16x16x32_bf16(a0, wf0a, aO0, 0, 0, 0);
            aO0 = __builtin_amdgcn_mfma_f32_16x16x32_bf16(a1, wf0b, aO0, 0, 0, 0);
            aO1 = __builtin_amdgcn_mfma_f32_16x16x32_bf16(a0, wf1a, aO1, 0, 0, 0);
            aO1 = __builtin_amdgcn_mfma_f32_16x16x32_bf16(a1, wf1b, aO1, 0, 0, 0);
        }
    }
    // offsets + bias -> wave-private s_soff[16 px][20] (same-wave DS ordering).
    float* soff = s_soff + wv * 320;
    {
        const float bia0 = b_off[l16];
        #pragma unroll
        for (int r = 0; r < 4; ++r)
            soff[(q * 4 + r) * 20 + l16] = aO0[r] + bia0;
        if (l16 < 2) {
            const float bia1 = b_off[16 + l16];
            #pragma unroll
            for (int r = 0; r < 4; ++r)
                soff[(q * 4 + r) * 20 + 16 + l16] = aO1[r] + bia1;
        }
    }

    // ---- residual prefetch (NCHW path): addresses are static ----
    float4 rv0 = {0,0,0,0}, rv1 = {0,0,0,0}, rv2 = {0,0,0,0}, rv3 = {0,0,0,0};
    if (!nhwc_out && addsrc != nullptr) {
        const float* ab = addsrc + ((size_t)b << 22);
        const int gbase = (h << 8) + w0 + pxb + (q << 2);
        rv0 = *(const float4*)(ab + ((l16 +  0) << 16) + gbase);
        rv1 = *(const float4*)(ab + ((l16 + 16) << 16) + gbase);
        rv2 = *(const float4*)(ab + ((l16 + 32) << 16) + gbase);
        rv3 = *(const float4*)(ab + ((l16 + 48) << 16) + gbase);
    }

    // ============ Gather (LDS) + conv MFMA, 9 taps, barrier-free ============
    float4a ac0 = {0.f, 0.f, 0.f, 0.f};   // oc  0..15
    float4a ac1 = {0.f, 0.f, 0.f, 0.f};   // oc 16..31
    float4a ac2 = {0.f, 0.f, 0.f, 0.f};   // oc 32..47
    float4a ac3 = {0.f, 0.f, 0.f, 0.f};   // oc 48..63
    {
        const unsigned short* bc0 = wtb + l16 * 576 + (q << 3);
        const unsigned short* bc1 = bc0 + 16 * 576;
        const unsigned short* bc2 = bc0 + 32 * 576;
        const unsigned short* bc3 = bc0 + 48 * 576;
        const int gx = w0 + pxb + l16;        // this thread's pixel column

        #pragma unroll
        for (int n = 0; n < 9; ++n) {
            const int rn = n / 3, cn = n - rn * 3;
            // geometry (exact r2 form)
            const float ox = soff[l16 * 20 + n];
            const float oy = soff[l16 * 20 + 9 + n];
            const float pxx = ox + (float)(h + rn);
            const float pyy = oy + (float)(gx + cn);
            const float fx = floorf(pxx), fy = floorf(pyy);
            const float qltx = fminf(fmaxf(fx, 0.f), 257.f);
            const float qlty = fminf(fmaxf(fy, 0.f), 257.f);
            const float qrbx = fminf(fmaxf(fx + 1.f, 0.f), 257.f);
            const float qrby = fminf(fmaxf(fy + 1.f, 0.f), 257.f);
            const float pxc = fminf(fmaxf(pxx, 0.f), 257.f);
            const float pyc = fminf(fmaxf(pyy, 0.f), 257.f);
            const float glt = (1.f + (qltx - pxc)) * (1.f + (qlty - pyc));
            const float grb = (1.f - (qrbx - pxc)) * (1.f - (qrby - pyc));
            const float glb = (1.f + (qltx - pxc)) * (1.f - (qrby - pyc));
            const float grt = (1.f - (qrbx - pxc)) * (1.f + (qlty - pyc));
            const int ilx = (int)qltx, ily = (int)qlty;
            const int irx = (int)qrbx, iry = (int)qrby;
            const bool b0 = (ilx >= 1) && (ilx <= 256) && (ily >= 1) && (ily <= 256);
            const bool b1 = (irx >= 1) && (irx <= 256) && (iry >= 1) && (iry <= 256);
            const bool b2 = (ilx >= 1) && (ilx <= 256) && (iry >= 1) && (iry <= 256);
            const bool b3 = (irx >= 1) && (irx <= 256) && (ily >= 1) && (ily <= 256);
            float4 G;
            G.x = b0 ? glt : 0.f;
            G.y = b1 ? grb : 0.f;
            G.z = b2 ? glb : 0.f;
            G.w = b3 ? grt : 0.f;

            // window coords (unpadded row = X-1 -> wr = X - h + 2; col likewise)
            const int wr0 = ilx - h + 2,  wc0 = ily - w0 + 2;   // lt row/col
            const int wr1 = irx - h + 2,  wc1 = iry - w0 + 2;   // rb row/col
            const bool ok =
                (!b0 || ((unsigned)wr0 <= 6u && (unsigned)wc0 <= 39u)) &&
                (!b1 || ((unsigned)wr1 <= 6u && (unsigned)wc1 <= 39u)) &&
                (!b2 || ((unsigned)wr0 <= 6u && (unsigned)wc1 <= 39u)) &&
                (!b3 || ((unsigned)wr1 <= 6u && (unsigned)wc0 <= 39u));

            uint4 A, Bv, Cv, Dv, A2, B2, C2, D2;
            if (ok) {
                // clamped (G=0 corners read in-bounds garbage, multiplied by 0)
                const int cr0 = wr0 < 0 ? 0 : (wr0 > 6 ? 6 : wr0);
                const int cr1 = wr1 < 0 ? 0 : (wr1 > 6 ? 6 : wr1);
                const int cc0 = wc0 < 0 ? 0 : (wc0 > 39 ? 39 : wc0);
                const int cc1 = wc1 < 0 ? 0 : (wc1 > 39 ? 39 : wc1);
                const int s0 = cc0 & 7, s1 = cc1 & 7;
                const unsigned short* plt = s_win + ((cr0 * WCOLS + cc0) << 6);
                const unsigned short* prb = s_win + ((cr1 * WCOLS + cc1) << 6);
                const unsigned short* plb = s_win + ((cr0 * WCOLS + cc1) << 6);
                const unsigned short* prt = s_win + ((cr1 * WCOLS + cc0) << 6);
                A  = *(const uint4*)(plt + ((q ^ s0) << 3));
                Bv = *(const uint4*)(prb + ((q ^ s1) << 3));
                Cv = *(const uint4*)(plb + ((q ^ s1) << 3));
                Dv = *(const uint4*)(prt + ((q ^ s0) << 3));
                A2 = *(const uint4*)(plt + (((q + 4) ^ s0) << 3));
                B2 = *(const uint4*)(prb + (((q + 4) ^ s1) << 3));
                C2 = *(const uint4*)(plb + (((q + 4) ^ s1) << 3));
                D2 = *(const uint4*)(prt + (((q + 4) ^ s0) << 3));
            } else {
                // rare fallback: global gathers (identical addressing to r2)
                const int L0 = b0 ? (((ilx - 1) << 8) + (ily - 1)) : 0;
                const int L1 = b1 ? (((irx - 1) << 8) + (iry - 1)) : 0;
                const int L2 = b2 ? (((ilx - 1) << 8) + (iry - 1)) : 0;
                const int L3 = b3 ? (((irx - 1) << 8) + (ily - 1)) : 0;
                A  = *(const uint4*)(srcb + (L0 << 6) + (q << 3));
                Bv = *(const uint4*)(srcb + (L1 << 6) + (q << 3));
                Cv = *(const uint4*)(srcb + (L2 << 6) + (q << 3));
                Dv = *(const uint4*)(srcb + (L3 << 6) + (q << 3));
                A2 = *(const uint4*)(srcb + (L0 << 6) + ((q + 4) << 3));
                B2 = *(const uint4*)(srcb + (L1 << 6) + ((q + 4) << 3));
                C2 = *(const uint4*)(srcb + (L2 << 6) + ((q + 4) << 3));
                D2 = *(const uint4*)(srcb + (L3 << 6) + ((q + 4) << 3));
            }

            // conv B fragments for this tap (L1-hot; issue before comb2 VALU)
            const short8 b0a = *(const short8*)(bc0 + n * 64);
            const short8 b0b = *(const short8*)(bc0 + n * 64 + 32);
            const short8 b1a = *(const short8*)(bc1 + n * 64);
            const short8 b1b = *(const short8*)(bc1 + n * 64 + 32);
            const short8 b2a = *(const short8*)(bc2 + n * 64);
            const short8 b2b = *(const short8*)(bc2 + n * 64 + 32);
            const short8 b3a = *(const short8*)(bc3 + n * 64);
            const short8 b3b = *(const short8*)(bc3 + n * 64 + 32);

            // bilinear combine -> A-fragments in registers
            uint4 r0v, r1v;
            r0v.x = comb2(A.x, Bv.x, Cv.x, Dv.x, G);
            r0v.y = comb2(A.y, Bv.y, Cv.y, Dv.y, G);
            r0v.z = comb2(A.z, Bv.z, Cv.z, Dv.z, G);
            r0v.w = comb2(A.w, Bv.w, Cv.w, Dv.w, G);
            r1v.x = comb2(A2.x, B2.x, C2.x, D2.x, G);
            r1v.y = comb2(A2.y, B2.y, C2.y, D2.y, G);
            r1v.z = comb2(A2.z, B2.z, C2.z, D2.z, G);
            r1v.w = comb2(A2.w, B2.w, C2.w, D2.w, G);
            const short8 a0 = __builtin_bit_cast(short8, r0v);   // ks = 2n
            const short8 a1 = __builtin_bit_cast(short8, r1v);   // ks = 2n+1

            ac0 = __builtin_amdgcn_mfma_f32_16x16x32_bf16(a0, b0a, ac0, 0, 0, 0);
            ac0 = __builtin_amdgcn_mfma_f32_16x16x32_bf16(a1, b0b, ac0, 0, 0, 0);
            ac1 = __builtin_amdgcn_mfma_f32_16x16x32_bf16(a0, b1a, ac1, 0, 0, 0);
            ac1 = __builtin_amdgcn_mfma_f32_16x16x32_bf16(a1, b1b, ac1, 0, 0, 0);
            ac2 = __builtin_amdgcn_mfma_f32_16x16x32_bf16(a0, b2a, ac2, 0, 0, 0);
            ac2 = __builtin_amdgcn_mfma_f32_16x16x32_bf16(a1, b2b, ac2, 0, 0, 0);
            ac3 = __builtin_amdgcn_mfma_f32_16x16x32_bf16(a0, b3a, ac3, 0, 0, 0);
            ac3 = __builtin_amdgcn_mfma_f32_16x16x32_bf16(a1, b3b, ac3, 0, 0, 0);
        }
    }

    // ============ Epilogue (no LDS, no barriers) ============
    // D layout: col = oc = l16 (+16t), row = px = q*4 + r.
    if (nhwc_out) {
        unsigned short* ob = (unsigned short*)out + ((size_t)b << 22);
        unsigned short* orow = ob + ((((h << 8) + w0 + pxb) << 6)) + l16;
        #pragma unroll
        for (int r = 0; r < 4; ++r) {
            const int px = q * 4 + r;
            float v0 = ac0[r], v1 = ac1[r], v2 = ac2[r], v3 = ac3[r];
            if (relu) {
                v0 = fmaxf(v0, 0.f); v1 = fmaxf(v1, 0.f);
                v2 = fmaxf(v2, 0.f); v3 = fmaxf(v3, 0.f);
            }
            unsigned short* p = orow + (px << 6);
            p[0]  = f2bf(v0);
            p[16] = f2bf(v1);
            p[32] = f2bf(v2);
            p[48] = f2bf(v3);
        }
    } else {
        // NCHW fp32: acc_t IS a contiguous px-quad float4 for channel 16t+l16.
        float* obf = (float*)out + ((size_t)b << 22);
        const int gbase = (h << 8) + w0 + pxb + (q << 2);
        const bool res = (addsrc != nullptr);
        float4 o0, o1, o2, o3;
        #pragma unroll
        for (int r = 0; r < 4; ++r) {
            float v0 = ac0[r], v1 = ac1[r], v2 = ac2[r], v3 = ac3[r];
            if (relu) {
                v0 = fmaxf(v0, 0.f); v1 = fmaxf(v1, 0.f);
                v2 = fmaxf(v2, 0.f); v3 = fmaxf(v3, 0.f);
            }
            o0[r] = v0; o1[r] = v1; o2[r] = v2; o3[r] = v3;
        }
        if (res) {
            o0.x += rv0.x; o0.y += rv0.y; o0.z += rv0.z; o0.w += rv0.w;
            o1.x += rv1.x; o1.y += rv1.y; o1.z += rv1.z; o1.w += rv1.w;
            o2.x += rv2.x; o2.y += rv2.y; o2.z += rv2.z; o2.w += rv2.w;
            o3.x += rv3.x; o3.y += rv3.y; o3.z += rv3.z; o3.w += rv3.w;
        }
        *(float4*)(obf + ((l16 +  0) << 16) + gbase) = o0;
        *(float4*)(obf + ((l16 + 16) << 16) + gbase) = o1;
        *(float4*)(obf + ((l16 + 32) << 16) + gbase) = o2;
        *(float4*)(obf + ((l16 + 48) << 16) + gbase) = o3;
    }
}

// ---------------------------------------------------------------------------
extern "C" void kernel_launch(void* const* d_in, const int* in_sizes, int n_in,
                              void* d_out, int out_size, void* d_ws, size_t ws_size,
                              hipStream_t stream) {
    const float* x      = (const float*)d_in[0];
    const float* w_off1 = (const float*)d_in[1];
    const float* b_off1 = (const float*)d_in[2];
    const float* w1     = (const float*)d_in[3];
    const float* w_off2 = (const float*)d_in[4];
    const float* b_off2 = (const float*)d_in[5];
    const float* w2     = (const float*)d_in[6];
    float* outp = (float*)d_out;

    // workspace: 16 MB xT(bf16) + 16 MB midT(bf16) + packed weights = 32.2 MB
    char* ws = (char*)d_ws;
    unsigned short* xT   = (unsigned short*)ws;                     // 16777216 B
    unsigned short* midT = (unsigned short*)(ws + 16777216);        // 16777216 B
    unsigned short* w1b  = (unsigned short*)(ws + 33554432);                    // 73728
    unsigned short* w2b  = (unsigned short*)(ws + 33554432 + 73728);            // 73728
    unsigned short* wob1 = (unsigned short*)(ws + 33554432 + 2 * 73728);        // 36864
    unsigned short* wob2 = (unsigned short*)(ws + 33554432 + 2 * 73728 + 36864);// 36864

    k_pack_all<<<432, 256, 0, stream>>>(w1, w2, w_off1, w_off2, w1b, w2b, wob1, wob2);

    dim3 gT(1024, 2);
    k_transpose_bf<<<gT, 256, 0, stream>>>(x, xT);

    dim3 gDef(8, 256, 2);   // (W/32, H, B); 128-thread blocks, 2 waves
    // layer 1: offsets + deform-conv(x), ReLU -> midT (NHWC bf16)
    k_fused<<<gDef, 128, 0, stream>>>(xT, wob1, b_off1, w1b, nullptr, midT, 1, 1);
    // layer 2: offsets + deform-conv(mid), + x residual -> out (NCHW fp32)
    k_fused<<<gDef, 128, 0, stream>>>(midT, wob2, b_off2, w2b, x, outp, 0, 0);
}